// Round 6
// baseline (183.337 us; speedup 1.0000x reference)
//
#include <hip/hip_runtime.h>
#include <hip/hip_bf16.h>

#define BIG 3.4e38f

constexpr int PLANE = 253 * 256;

// ---------- top-5 helpers ----------

// Merge two ascending sorted 5-lists, keep the 5 smallest in a[].
__device__ __forceinline__ void merge5(float a[5], const float* b) {
    float r[5];
#pragma unroll
    for (int k = 0; k < 5; ++k) {
        float best = BIG;
#pragma unroll
        for (int i = 0; i <= k + 1; ++i) {
            const int j = k + 1 - i;
            float va = (i == 0) ? -BIG : a[i - 1];
            float vb = (j == 0) ? -BIG : b[j - 1];
            best = fminf(best, fmaxf(va, vb));
        }
        r[k] = best;
    }
#pragma unroll
    for (int k = 0; k < 5; ++k) a[k] = r[k];
}

__device__ __forceinline__ void top5_insert(float m[5], float d) {
    if (d < m[4]) {
        m[4] = d;
#pragma unroll
        for (int k = 4; k > 0; --k) {
            float lo = fminf(m[k - 1], m[k]);
            float hi = fmaxf(m[k - 1], m[k]);
            m[k - 1] = lo;
            m[k] = hi;
        }
    }
}

// 5 smallest across wave, one value per lane (iterative min-extract;
// exact w.r.t. duplicates via ballot+ffs). Result sorted, in all lanes.
__device__ __forceinline__ void wave_top5_extract(float d, int lane,
                                                  float r[5]) {
#pragma unroll
    for (int k = 0; k < 5; ++k) {
        float v = d;
#pragma unroll
        for (int off = 32; off >= 1; off >>= 1)
            v = fminf(v, __shfl_xor(v, off, 64));
        r[k] = v;
        const unsigned long long ball = __ballot(d == v);
        const int src = (int)__ffsll(ball) - 1;
        if (lane == src) d = BIG;
    }
}

// 5 smallest of the union of per-lane ascending 5-lists (k-way merge by
// head-pop: global min of heads is the global min; pop exactly one).
__device__ __forceinline__ void wave_top5_pop(float m[5], int lane,
                                              float r[5]) {
#pragma unroll
    for (int k = 0; k < 5; ++k) {
        float v = m[0];
#pragma unroll
        for (int off = 32; off >= 1; off >>= 1)
            v = fminf(v, __shfl_xor(v, off, 64));
        r[k] = v;
        const unsigned long long ball = __ballot(m[0] == v);
        const int src = (int)__ffsll(ball) - 1;
        if (lane == src) {
            m[0] = m[1]; m[1] = m[2]; m[2] = m[3]; m[3] = m[4]; m[4] = BIG;
        }
    }
}

__device__ __forceinline__ void wave_merge_top5(float m[5]) {
#pragma unroll
    for (int off = 1; off < 64; off <<= 1) {
        float o[5];
#pragma unroll
        for (int k = 0; k < 5; ++k) o[k] = __shfl_xor(m[k], off, 64);
        merge5(m, o);
    }
}

__device__ __forceinline__ bool block_merge_top5(float m[5], float (*s_top)[5],
                                                 float r[5]) {
    const int wid = threadIdx.x >> 6;
    if ((threadIdx.x & 63) == 0) {
#pragma unroll
        for (int k = 0; k < 5; ++k) s_top[wid][k] = m[k];
    }
    __syncthreads();
    if (threadIdx.x == 0) {
#pragma unroll
        for (int k = 0; k < 5; ++k) r[k] = s_top[0][k];
        merge5(r, s_top[1]);
        merge5(r, s_top[2]);
        merge5(r, s_top[3]);
        return true;
    }
    return false;
}

// ---------- K1 v6: chunk-split partial planes, SGPR tv, 2 pos/lane ----
// Proven round-0 skeleton (its K1+K2 ≈ 30 µs beat every fused variant).
// Upgrades: tv read straight from tgt0 via wave-uniform scalar loads
// (readfirstlane'd pos -> s_load; no pack kernel, no LDS table, no
// exchange; scale-0 path uses ZERO LDS). 2 positions/lane from one
// 8B-aligned float4. Finer grid for tail balance: 8 chunks x 64 row-
// quads x 2 col-halves = 1024 blocks (+64 scale-1) of 256 threads.
// Per (c,i,t): 1 shared s_load row + 12 VALU; 10 float2 partial stores.
// Blocks [0,64): scale-1 (C=128, ps=1) full dist + block top-5 -> p2b.
__global__ __launch_bounds__(256) void dist_all_kernel(
    const float* __restrict__ src0, const float* __restrict__ tgt0,
    const int* __restrict__ pos0, const float* __restrict__ src1,
    const float* __restrict__ tgt1, const int* __restrict__ pos1,
    float* __restrict__ dist0, float* __restrict__ p2b,
    int* __restrict__ counter) {
    __shared__ float stp[4][5][5];
    const int tid = threadIdx.x;
    const int lane = tid & 63;
    const int wv = tid >> 6;
    const int bx = blockIdx.x;

    if (bx == 0 && tid == 0) *counter = 0;  // election counter for K2

    if (bx >= 64) {
        // ---- scale 0: C=64, H=W=256, ps=3, chunk = 8 channels ----
        const int b = bx - 64;
        const int chunk = b >> 7;         // 0..7
        const int tile = b & 127;         // 64 quads x 2 halves
        const int h = (tile >> 1) * 4 + wv;
        const int hl = (h <= 252) ? h : 252;  // clamp loads in-bounds
        const int w0 = ((tile & 1) << 7) + 2 * lane;  // 0..254 even

        int th[10], tw[10];
#pragma unroll
        for (int t = 0; t < 10; ++t) {
            th[t] = __builtin_amdgcn_readfirstlane(pos0[2 * t]);
            tw[t] = __builtin_amdgcn_readfirstlane(pos0[2 * t + 1]);
        }

        float acc[10][2];
#pragma unroll
        for (int t = 0; t < 10; ++t) acc[t][0] = acc[t][1] = 0.f;

        const int c0 = chunk * 8;
        const float* sb = src0 + (size_t)c0 * 65536 + hl * 256 + w0;
        const float* tb = tgt0 + (size_t)c0 * 65536;
        for (int c = 0; c < 8; ++c) {
            const float* row = sb + (size_t)c * 65536;
            const float* tgc = tb + (size_t)c * 65536;
#pragma unroll
            for (int i = 0; i < 3; ++i) {
                const float4 a = *(const float4*)(row + i * 256);
#pragma unroll
                for (int t = 0; t < 10; ++t) {
                    const float* tg = tgc + (th[t] + i) * 256 + tw[t];
                    const float t0 = tg[0], t1 = tg[1], t2 = tg[2];  // s_load
                    acc[t][0] += fabsf(a.x - t0) + fabsf(a.y - t1) +
                                 fabsf(a.z - t2);
                    acc[t][1] += fabsf(a.y - t0) + fabsf(a.z - t1) +
                                 fabsf(a.w - t2);
                }
            }
        }

        if (h < 253) {
            float* dp = dist0 + (size_t)chunk * 10 * PLANE + h * 256 + w0;
#pragma unroll
            for (int t = 0; t < 10; ++t) {
                float2 o = {acc[t][0], acc[t][1]};
                *(float2*)(dp + (size_t)t * PLANE) = o;
            }
        }
    } else {
        // ---- scale 1: C=128, H=W=128, ps=1; 2 rows per block ----
        const int bb = bx;
        int th[5], tw[5];
#pragma unroll
        for (int t = 0; t < 5; ++t) {
            th[t] = __builtin_amdgcn_readfirstlane(pos1[2 * t]);
            tw[t] = __builtin_amdgcn_readfirstlane(pos1[2 * t + 1]);
        }
        const int w = tid & 127;
        const int h1 = bb * 2 + (tid >> 7);  // 0..127
        float acc[5] = {0.f, 0.f, 0.f, 0.f, 0.f};
        const float* sp = src1 + h1 * 128 + w;
        for (int c = 0; c < 128; ++c) {
            const float v = sp[(size_t)c * 16384];
#pragma unroll
            for (int t = 0; t < 5; ++t) {
                const float tv =
                    tgt1[(size_t)c * 16384 + th[t] * 128 + tw[t]];  // s_load
                acc[t] += fabsf(v - tv);
            }
        }
        const bool valid = (w < 127) && (h1 < 127);
#pragma unroll
        for (int t = 0; t < 5; ++t) {
            float r[5];
            wave_top5_extract(valid ? acc[t] : BIG, lane, r);
            if (lane == 0) {
#pragma unroll
                for (int k = 0; k < 5; ++k) stp[wv][t][k] = r[k];
            }
        }
        __syncthreads();
        if (tid < 5) {
            float r[5];
#pragma unroll
            for (int k = 0; k < 5; ++k) r[k] = stp[0][tid][k];
            merge5(r, stp[1][tid]);
            merge5(r, stp[2][tid]);
            merge5(r, stp[3][tid]);
            float* dst = p2b + (tid * 64 + bb) * 5;
#pragma unroll
            for (int k = 0; k < 5; ++k) dst[k] = r[k];
        }
    }
}

// ---------- K2 v6: summed-plane top-5 + folded final merge ------------
// Grid (64, 10): 640 blocks, 1 float4/thread over the 8 chunk planes.
// Last-finishing block (device-scope atomic election; counter zeroed by
// K1) performs the final 15-target merge + scalar output -> removes the
// separate K3 launch. Output word: high16 = f32 bits, low16 = RNE bf16.
__global__ __launch_bounds__(256) void top5_stage_merge_kernel(
    const float* __restrict__ dist0, float* __restrict__ p2a,
    const float* __restrict__ p2b, int* __restrict__ counter,
    unsigned int* __restrict__ out) {
    __shared__ float s_top[4][5];
    __shared__ float s_sum[15];
    __shared__ int s_flag;
    const int tid = threadIdx.x;
    const int lane = tid & 63;
    const int t = blockIdx.y;
    const int f = blockIdx.x * 256 + tid;

    float m[5] = {BIG, BIG, BIG, BIG, BIG};
    if (f < PLANE / 4) {
        const float* base = dist0 + (size_t)t * PLANE + f * 4;
        float4 s = *(const float4*)base;
#pragma unroll
        for (int ch = 1; ch < 8; ++ch) {
            const float4 u = *(const float4*)(base + (size_t)ch * 10 * PLANE);
            s.x += u.x; s.y += u.y; s.z += u.z; s.w += u.w;
        }
        const int w0 = (f * 4) & 255;
        top5_insert(m, (w0 + 0 < 253) ? s.x : BIG);
        top5_insert(m, (w0 + 1 < 253) ? s.y : BIG);
        top5_insert(m, (w0 + 2 < 253) ? s.z : BIG);
        top5_insert(m, (w0 + 3 < 253) ? s.w : BIG);
    }
    float r[5];
    wave_top5_pop(m, lane, r);
    float rr[5];
    if (block_merge_top5(r, s_top, rr)) {
        float* dst = p2a + (t * 64 + blockIdx.x) * 5;
#pragma unroll
        for (int k = 0; k < 5; ++k) dst[k] = rr[k];
    }

    // ---- last-block election (release p2a write, then count) ----
    __threadfence();
    if (tid == 0) s_flag = (atomicAdd(counter, 1) == 64 * 10 - 1) ? 1 : 0;
    __syncthreads();
    if (!s_flag) return;
    __threadfence();  // acquire: all blocks' p2a writes now visible

    const int wv = tid >> 6;
#pragma unroll
    for (int rt = 0; rt < 4; ++rt) {
        const int tt = wv * 4 + rt;
        if (tt < 15) {
            const float* base2 =
                (tt < 10) ? p2a + tt * 320 : p2b + (tt - 10) * 320;
            const float scale =
                (tt < 10) ? 1.f / (576.f * 5.f) : 1.f / (128.f * 5.f);
            float mm[5] = {BIG, BIG, BIG, BIG, BIG};
#pragma unroll
            for (int b0 = 0; b0 < 5; ++b0)
                top5_insert(mm, base2[b0 * 64 + lane]);
            float rr2[5];
            wave_top5_pop(mm, lane, rr2);
            if (lane == 0)
                s_sum[tt] =
                    (rr2[0] + rr2[1] + rr2[2] + rr2[3] + rr2[4]) * scale;
        }
    }
    __syncthreads();
    if (tid == 0) {
        float total = 0.f;
#pragma unroll
        for (int k = 0; k < 15; ++k) total += s_sum[k];
        union { float fl; unsigned int i; } uf;
        uf.fl = total * 0.1f;
        unsigned int bf = (uf.i + 0x7FFFu + ((uf.i >> 16) & 1u)) >> 16;
        out[0] = (uf.i & 0xFFFF0000u) | (bf & 0xFFFFu);
    }
}

// ---------- fallback path (proven, tiny ws) ----------
__global__ __launch_bounds__(256) void final_merge_kernel(
    const float* __restrict__ p2a, int na,
    const float* __restrict__ p2b, int nb,
    unsigned int* __restrict__ out) {
    __shared__ float s_sum[15];
    const int lane = threadIdx.x & 63;
    const int wv = threadIdx.x >> 6;
#pragma unroll
    for (int rt = 0; rt < 4; ++rt) {
        const int t = wv * 4 + rt;
        if (t < 15) {
            const float* base = (t < 10) ? p2a + t * na : p2b + (t - 10) * nb;
            const int n = (t < 10) ? na : nb;
            const float scale =
                (t < 10) ? 1.f / (576.f * 5.f) : 1.f / (128.f * 5.f);
            float m[5] = {BIG, BIG, BIG, BIG, BIG};
            for (int b0 = 0; b0 < n; b0 += 64)
                if (b0 + lane < n) top5_insert(m, base[b0 + lane]);
            wave_merge_top5(m);
            if (lane == 0)
                s_sum[t] = (m[0] + m[1] + m[2] + m[3] + m[4]) * scale;
        }
    }
    __syncthreads();
    if (threadIdx.x == 0) {
        float total = 0.f;
#pragma unroll
        for (int t = 0; t < 15; ++t) total += s_sum[t];
        union { float f; unsigned int i; } uf;
        uf.f = total * 0.1f;
        unsigned int bf = (uf.i + 0x7FFFu + ((uf.i >> 16) & 1u)) >> 16;
        out[0] = (uf.i & 0xFFFF0000u) | (bf & 0xFFFFu);
    }
}

template <int C, int H, int PS, int WM>
__global__ __launch_bounds__(256) void dist_top5_kernel(
    const float* __restrict__ src, const float* __restrict__ tgt,
    const int* __restrict__ pos, float* __restrict__ part) {
    constexpr int W = H;
    constexpr int K = C * PS * PS;
    constexpr int P = WM * WM;
    __shared__ float tlv[K];
    __shared__ float s_top[4][5];
    const int t = blockIdx.y;
    const int th = pos[2 * t], tw = pos[2 * t + 1];
    for (int idx = threadIdx.x; idx < K; idx += 256) {
        int c = idx / (PS * PS);
        int rem = idx - c * PS * PS;
        int i = rem / PS, j = rem - i * PS;
        tlv[idx] = tgt[(c * H + th + i) * W + tw + j];
    }
    __syncthreads();
    const int p = blockIdx.x * 256 + threadIdx.x;
    float d = BIG;
    if (p < P) {
        const int h = p / WM, w = p - h * WM;
        float acc = 0.f;
        for (int c = 0; c < C; ++c)
#pragma unroll
            for (int i = 0; i < PS; ++i) {
                const float* r = src + (c * H + h + i) * W + w;
                const float* tr = &tlv[(c * PS + i) * PS];
#pragma unroll
                for (int j = 0; j < PS; ++j) acc += fabsf(r[j] - tr[j]);
            }
        d = acc;
    }
    float m[5] = {d, BIG, BIG, BIG, BIG};
    wave_merge_top5(m);
    float r[5];
    if (block_merge_top5(m, s_top, r)) {
        float* dst = part + (t * gridDim.x + blockIdx.x) * 5;
#pragma unroll
        for (int k = 0; k < 5; ++k) dst[k] = r[k];
    }
}

extern "C" void kernel_launch(void* const* d_in, const int* in_sizes, int n_in,
                              void* d_out, int out_size, void* d_ws, size_t ws_size,
                              hipStream_t stream) {
    const float* src0 = (const float*)d_in[0];  // [1,64,256,256] f32
    const float* tgt0 = (const float*)d_in[1];
    const float* src1 = (const float*)d_in[2];  // [1,128,128,128] f32
    const float* tgt1 = (const float*)d_in[3];
    const int* pos0 = (const int*)d_in[4];      // [10,2]
    const int* pos1 = (const int*)d_in[5];      // [5,2]
    unsigned int* out = (unsigned int*)d_out;

    constexpr size_t NDIST = (size_t)8 * 10 * PLANE;  // 5.18M floats
    constexpr size_t NP2A = 10 * 64 * 5;              // 3200
    constexpr size_t NP2B = 5 * 64 * 5;               // 1600
    const size_t need = (NDIST + NP2A + NP2B + 4) * 4;  // ~20.75 MB

    if (ws_size >= need) {
        float* dist0 = (float*)d_ws;
        float* p2a = dist0 + NDIST;
        float* p2b = p2a + NP2A;
        int* counter = (int*)(p2b + NP2B);

        // K1: scale-1 (64 blocks) + scale-0 chunk partials (1024 blocks).
        dist_all_kernel<<<dim3(1088), 256, 0, stream>>>(
            src0, tgt0, pos0, src1, tgt1, pos1, dist0, p2b, counter);
        // K2: summed-plane top-5 + folded final merge (last block).
        top5_stage_merge_kernel<<<dim3(64, 10), 256, 0, stream>>>(
            dist0, p2a, p2b, counter, out);
    } else {
        // Fallback: proven path (~57KB of ws).
        float* part0 = (float*)d_ws;
        float* part1 = part0 + 10 * 251 * 5;
        dist_top5_kernel<64, 256, 3, 253>
            <<<dim3(251, 10), 256, 0, stream>>>(src0, tgt0, pos0, part0);
        dist_top5_kernel<128, 128, 1, 127>
            <<<dim3(64, 5), 256, 0, stream>>>(src1, tgt1, pos1, part1);
        final_merge_kernel<<<dim3(1), 256, 0, stream>>>(part0, 1255, part1, 320, out);
    }
}

// Round 7
// 138.683 us; speedup vs baseline: 1.3220x; 1.3220x over previous
//
#include <hip/hip_runtime.h>
#include <hip/hip_bf16.h>

#define BIG 3.4e38f

constexpr int PLANE = 253 * 256;

// ---------- top-5 helpers ----------

// Merge two ascending sorted 5-lists, keep the 5 smallest in a[].
__device__ __forceinline__ void merge5(float a[5], const float* b) {
    float r[5];
#pragma unroll
    for (int k = 0; k < 5; ++k) {
        float best = BIG;
#pragma unroll
        for (int i = 0; i <= k + 1; ++i) {
            const int j = k + 1 - i;
            float va = (i == 0) ? -BIG : a[i - 1];
            float vb = (j == 0) ? -BIG : b[j - 1];
            best = fminf(best, fmaxf(va, vb));
        }
        r[k] = best;
    }
#pragma unroll
    for (int k = 0; k < 5; ++k) a[k] = r[k];
}

__device__ __forceinline__ void top5_insert(float m[5], float d) {
    if (d < m[4]) {
        m[4] = d;
#pragma unroll
        for (int k = 4; k > 0; --k) {
            float lo = fminf(m[k - 1], m[k]);
            float hi = fmaxf(m[k - 1], m[k]);
            m[k - 1] = lo;
            m[k] = hi;
        }
    }
}

// 5 smallest across wave, one value per lane (iterative min-extract;
// exact w.r.t. duplicates via ballot+ffs). Result sorted, in all lanes.
__device__ __forceinline__ void wave_top5_extract(float d, int lane,
                                                  float r[5]) {
#pragma unroll
    for (int k = 0; k < 5; ++k) {
        float v = d;
#pragma unroll
        for (int off = 32; off >= 1; off >>= 1)
            v = fminf(v, __shfl_xor(v, off, 64));
        r[k] = v;
        const unsigned long long ball = __ballot(d == v);
        const int src = (int)__ffsll(ball) - 1;
        if (lane == src) d = BIG;
    }
}

// 5 smallest of the union of per-lane ascending 5-lists (k-way merge by
// head-pop: global min of heads is the global min; pop exactly one).
__device__ __forceinline__ void wave_top5_pop(float m[5], int lane,
                                              float r[5]) {
#pragma unroll
    for (int k = 0; k < 5; ++k) {
        float v = m[0];
#pragma unroll
        for (int off = 32; off >= 1; off >>= 1)
            v = fminf(v, __shfl_xor(v, off, 64));
        r[k] = v;
        const unsigned long long ball = __ballot(m[0] == v);
        const int src = (int)__ffsll(ball) - 1;
        if (lane == src) {
            m[0] = m[1]; m[1] = m[2]; m[2] = m[3]; m[3] = m[4]; m[4] = BIG;
        }
    }
}

__device__ __forceinline__ void wave_merge_top5(float m[5]) {
#pragma unroll
    for (int off = 1; off < 64; off <<= 1) {
        float o[5];
#pragma unroll
        for (int k = 0; k < 5; ++k) o[k] = __shfl_xor(m[k], off, 64);
        merge5(m, o);
    }
}

__device__ __forceinline__ bool block_merge_top5(float m[5], float (*s_top)[5],
                                                 float r[5]) {
    const int wid = threadIdx.x >> 6;
    if ((threadIdx.x & 63) == 0) {
#pragma unroll
        for (int k = 0; k < 5; ++k) s_top[wid][k] = m[k];
    }
    __syncthreads();
    if (threadIdx.x == 0) {
#pragma unroll
        for (int k = 0; k < 5; ++k) r[k] = s_top[0][k];
        merge5(r, s_top[1]);
        merge5(r, s_top[2]);
        merge5(r, s_top[3]);
        return true;
    }
    return false;
}

// ---------- K1: chunk-split partial planes, SGPR tv, 2 pos/lane --------
// (Identical compute to round-6's passing K1; election counter removed.)
// tv read straight from tgt0 via wave-uniform scalar loads
// (readfirstlane'd pos -> s_load; no pack kernel, no LDS table, no
// exchange; scale-0 path uses ZERO LDS). 2 positions/lane from one
// 8B-aligned float4. 8 chunks x 64 row-quads x 2 col-halves = 1024
// blocks (+64 scale-1) of 256 threads.
// Blocks [0,64): scale-1 (C=128, ps=1) full dist + block top-5 -> p2b.
__global__ __launch_bounds__(256) void dist_all_kernel(
    const float* __restrict__ src0, const float* __restrict__ tgt0,
    const int* __restrict__ pos0, const float* __restrict__ src1,
    const float* __restrict__ tgt1, const int* __restrict__ pos1,
    float* __restrict__ dist0, float* __restrict__ p2b) {
    __shared__ float stp[4][5][5];
    const int tid = threadIdx.x;
    const int lane = tid & 63;
    const int wv = tid >> 6;
    const int bx = blockIdx.x;

    if (bx >= 64) {
        // ---- scale 0: C=64, H=W=256, ps=3, chunk = 8 channels ----
        const int b = bx - 64;
        const int chunk = b >> 7;         // 0..7
        const int tile = b & 127;         // 64 quads x 2 halves
        const int h = (tile >> 1) * 4 + wv;
        const int hl = (h <= 252) ? h : 252;  // clamp loads in-bounds
        const int w0 = ((tile & 1) << 7) + 2 * lane;  // 0..254 even

        int th[10], tw[10];
#pragma unroll
        for (int t = 0; t < 10; ++t) {
            th[t] = __builtin_amdgcn_readfirstlane(pos0[2 * t]);
            tw[t] = __builtin_amdgcn_readfirstlane(pos0[2 * t + 1]);
        }

        float acc[10][2];
#pragma unroll
        for (int t = 0; t < 10; ++t) acc[t][0] = acc[t][1] = 0.f;

        const int c0 = chunk * 8;
        const float* sb = src0 + (size_t)c0 * 65536 + hl * 256 + w0;
        const float* tb = tgt0 + (size_t)c0 * 65536;
        for (int c = 0; c < 8; ++c) {
            const float* row = sb + (size_t)c * 65536;
            const float* tgc = tb + (size_t)c * 65536;
#pragma unroll
            for (int i = 0; i < 3; ++i) {
                const float4 a = *(const float4*)(row + i * 256);
#pragma unroll
                for (int t = 0; t < 10; ++t) {
                    const float* tg = tgc + (th[t] + i) * 256 + tw[t];
                    const float t0 = tg[0], t1 = tg[1], t2 = tg[2];  // s_load
                    acc[t][0] += fabsf(a.x - t0) + fabsf(a.y - t1) +
                                 fabsf(a.z - t2);
                    acc[t][1] += fabsf(a.y - t0) + fabsf(a.z - t1) +
                                 fabsf(a.w - t2);
                }
            }
        }

        if (h < 253) {
            float* dp = dist0 + (size_t)chunk * 10 * PLANE + h * 256 + w0;
#pragma unroll
            for (int t = 0; t < 10; ++t) {
                float2 o = {acc[t][0], acc[t][1]};
                *(float2*)(dp + (size_t)t * PLANE) = o;
            }
        }
    } else {
        // ---- scale 1: C=128, H=W=128, ps=1; 2 rows per block ----
        const int bb = bx;
        int th[5], tw[5];
#pragma unroll
        for (int t = 0; t < 5; ++t) {
            th[t] = __builtin_amdgcn_readfirstlane(pos1[2 * t]);
            tw[t] = __builtin_amdgcn_readfirstlane(pos1[2 * t + 1]);
        }
        const int w = tid & 127;
        const int h1 = bb * 2 + (tid >> 7);  // 0..127
        float acc[5] = {0.f, 0.f, 0.f, 0.f, 0.f};
        const float* sp = src1 + h1 * 128 + w;
        for (int c = 0; c < 128; ++c) {
            const float v = sp[(size_t)c * 16384];
#pragma unroll
            for (int t = 0; t < 5; ++t) {
                const float tv =
                    tgt1[(size_t)c * 16384 + th[t] * 128 + tw[t]];  // s_load
                acc[t] += fabsf(v - tv);
            }
        }
        const bool valid = (w < 127) && (h1 < 127);
#pragma unroll
        for (int t = 0; t < 5; ++t) {
            float r[5];
            wave_top5_extract(valid ? acc[t] : BIG, lane, r);
            if (lane == 0) {
#pragma unroll
                for (int k = 0; k < 5; ++k) stp[wv][t][k] = r[k];
            }
        }
        __syncthreads();
        if (tid < 5) {
            float r[5];
#pragma unroll
            for (int k = 0; k < 5; ++k) r[k] = stp[0][tid][k];
            merge5(r, stp[1][tid]);
            merge5(r, stp[2][tid]);
            merge5(r, stp[3][tid]);
            float* dst = p2b + (tid * 64 + bb) * 5;
#pragma unroll
            for (int k = 0; k < 5; ++k) dst[k] = r[k];
        }
    }
}

// ---------- K2: summed-plane top-5 (NO election, NO fences) ------------
// Round-6 lesson: last-block election's __threadfence() = device-scope
// buffer_wbl2/inv per wave x 640 blocks -> 71 µs at 1.35% VALUBusy and
// trashed L2. A separate 1-block K3 launch is ~2 µs. Never again.
// Grid (64, 10): 1 float4/thread over the 8 chunk planes.
__global__ __launch_bounds__(256) void top5_stage_kernel(
    const float* __restrict__ dist0, float* __restrict__ p2a) {
    __shared__ float s_top[4][5];
    const int tid = threadIdx.x;
    const int lane = tid & 63;
    const int t = blockIdx.y;
    const int f = blockIdx.x * 256 + tid;

    float m[5] = {BIG, BIG, BIG, BIG, BIG};
    if (f < PLANE / 4) {
        const float* base = dist0 + (size_t)t * PLANE + f * 4;
        float4 s = *(const float4*)base;
#pragma unroll
        for (int ch = 1; ch < 8; ++ch) {
            const float4 u = *(const float4*)(base + (size_t)ch * 10 * PLANE);
            s.x += u.x; s.y += u.y; s.z += u.z; s.w += u.w;
        }
        const int w0 = (f * 4) & 255;
        top5_insert(m, (w0 + 0 < 253) ? s.x : BIG);
        top5_insert(m, (w0 + 1 < 253) ? s.y : BIG);
        top5_insert(m, (w0 + 2 < 253) ? s.z : BIG);
        top5_insert(m, (w0 + 3 < 253) ? s.w : BIG);
    }
    float r[5];
    wave_top5_pop(m, lane, r);
    float rr[5];
    if (block_merge_top5(r, s_top, rr)) {
        float* dst = p2a + (t * 64 + blockIdx.x) * 5;
#pragma unroll
        for (int k = 0; k < 5; ++k) dst[k] = rr[k];
    }
}

// ---------- K3: parallel-over-targets final merge + scalar write --------
// Output word: high16 = f32 bits, low16 = RNE bf16 bits (dtype-proof).
__global__ __launch_bounds__(256) void final_merge_kernel(
    const float* __restrict__ p2a, int na,
    const float* __restrict__ p2b, int nb,
    unsigned int* __restrict__ out) {
    __shared__ float s_sum[15];
    const int lane = threadIdx.x & 63;
    const int wv = threadIdx.x >> 6;
#pragma unroll
    for (int rt = 0; rt < 4; ++rt) {
        const int t = wv * 4 + rt;
        if (t < 15) {
            const float* base = (t < 10) ? p2a + t * na : p2b + (t - 10) * nb;
            const int n = (t < 10) ? na : nb;
            const float scale =
                (t < 10) ? 1.f / (576.f * 5.f) : 1.f / (128.f * 5.f);
            float m[5] = {BIG, BIG, BIG, BIG, BIG};
            for (int b0 = 0; b0 < n; b0 += 64)
                if (b0 + lane < n) top5_insert(m, base[b0 + lane]);
            wave_merge_top5(m);
            if (lane == 0)
                s_sum[t] = (m[0] + m[1] + m[2] + m[3] + m[4]) * scale;
        }
    }
    __syncthreads();
    if (threadIdx.x == 0) {
        float total = 0.f;
#pragma unroll
        for (int t = 0; t < 15; ++t) total += s_sum[t];
        union { float f; unsigned int i; } uf;
        uf.f = total * 0.1f;
        unsigned int bf = (uf.i + 0x7FFFu + ((uf.i >> 16) & 1u)) >> 16;
        out[0] = (uf.i & 0xFFFF0000u) | (bf & 0xFFFFu);
    }
}

// ---------- fallback path (proven, tiny ws) ----------
template <int C, int H, int PS, int WM>
__global__ __launch_bounds__(256) void dist_top5_kernel(
    const float* __restrict__ src, const float* __restrict__ tgt,
    const int* __restrict__ pos, float* __restrict__ part) {
    constexpr int W = H;
    constexpr int K = C * PS * PS;
    constexpr int P = WM * WM;
    __shared__ float tlv[K];
    __shared__ float s_top[4][5];
    const int t = blockIdx.y;
    const int th = pos[2 * t], tw = pos[2 * t + 1];
    for (int idx = threadIdx.x; idx < K; idx += 256) {
        int c = idx / (PS * PS);
        int rem = idx - c * PS * PS;
        int i = rem / PS, j = rem - i * PS;
        tlv[idx] = tgt[(c * H + th + i) * W + tw + j];
    }
    __syncthreads();
    const int p = blockIdx.x * 256 + threadIdx.x;
    float d = BIG;
    if (p < P) {
        const int h = p / WM, w = p - h * WM;
        float acc = 0.f;
        for (int c = 0; c < C; ++c)
#pragma unroll
            for (int i = 0; i < PS; ++i) {
                const float* r = src + (c * H + h + i) * W + w;
                const float* tr = &tlv[(c * PS + i) * PS];
#pragma unroll
                for (int j = 0; j < PS; ++j) acc += fabsf(r[j] - tr[j]);
            }
        d = acc;
    }
    float m[5] = {d, BIG, BIG, BIG, BIG};
    wave_merge_top5(m);
    float r[5];
    if (block_merge_top5(m, s_top, r)) {
        float* dst = part + (t * gridDim.x + blockIdx.x) * 5;
#pragma unroll
        for (int k = 0; k < 5; ++k) dst[k] = r[k];
    }
}

extern "C" void kernel_launch(void* const* d_in, const int* in_sizes, int n_in,
                              void* d_out, int out_size, void* d_ws, size_t ws_size,
                              hipStream_t stream) {
    const float* src0 = (const float*)d_in[0];  // [1,64,256,256] f32
    const float* tgt0 = (const float*)d_in[1];
    const float* src1 = (const float*)d_in[2];  // [1,128,128,128] f32
    const float* tgt1 = (const float*)d_in[3];
    const int* pos0 = (const int*)d_in[4];      // [10,2]
    const int* pos1 = (const int*)d_in[5];      // [5,2]
    unsigned int* out = (unsigned int*)d_out;

    constexpr size_t NDIST = (size_t)8 * 10 * PLANE;  // 5.18M floats
    constexpr size_t NP2A = 10 * 64 * 5;              // 3200
    constexpr size_t NP2B = 5 * 64 * 5;               // 1600
    const size_t need = (NDIST + NP2A + NP2B) * 4;    // ~20.75 MB

    if (ws_size >= need) {
        float* dist0 = (float*)d_ws;
        float* p2a = dist0 + NDIST;
        float* p2b = p2a + NP2A;

        // K1: scale-1 (64 blocks) + scale-0 chunk partials (1024 blocks).
        dist_all_kernel<<<dim3(1088), 256, 0, stream>>>(
            src0, tgt0, pos0, src1, tgt1, pos1, dist0, p2b);
        // K2: summed-plane top-5 per (target, 64-block slice).
        top5_stage_kernel<<<dim3(64, 10), 256, 0, stream>>>(dist0, p2a);
        // K3: final merge (10 x 320 values + 5 x 320 values).
        final_merge_kernel<<<dim3(1), 256, 0, stream>>>(p2a, 320, p2b, 320,
                                                        out);
    } else {
        // Fallback: proven path (~57KB of ws).
        float* part0 = (float*)d_ws;
        float* part1 = part0 + 10 * 251 * 5;
        dist_top5_kernel<64, 256, 3, 253>
            <<<dim3(251, 10), 256, 0, stream>>>(src0, tgt0, pos0, part0);
        dist_top5_kernel<128, 128, 1, 127>
            <<<dim3(64, 5), 256, 0, stream>>>(src1, tgt1, pos1, part1);
        final_merge_kernel<<<dim3(1), 256, 0, stream>>>(part0, 1255, part1, 320, out);
    }
}